// Round 2
// baseline (567.713 us; speedup 1.0000x reference)
//
#include <hip/hip_runtime.h>
#include <hip/hip_cooperative_groups.h>
#include <math.h>

namespace cg = cooperative_groups;

// ---------------------------------------------------------------------------
// LocalTransformerBlock2d: B=1, C=256, H=W=56 (N=3136), 8 heads x d=32,
// 7x7 local window. fp32 in/out; bf16 MFMA GEMMs.
// Single cooperative kernel, 7 phases with grid.sync() between:
//   P0 cvt weights + LN1(+transpose)  P1 qkv GEMM   P2 local attn
//   P3 proj GEMM(+resid)              P4 LN2        P5 fc1 GEMM(+gelu)
//   P6 fc2 GEMM(+resid, transposed output)
// ---------------------------------------------------------------------------

typedef unsigned int uint;
typedef unsigned short ushort;
typedef __attribute__((ext_vector_type(8))) short short8;   // 8 bf16
typedef __attribute__((ext_vector_type(4))) float floatx4;  // MFMA acc
typedef __attribute__((ext_vector_type(4))) unsigned short ushort4v;

#define AS1(p) (const __attribute__((address_space(1))) void*)(p)
#define AS3(p) (__attribute__((address_space(3))) void*)(p)

#define NBLK 512
#define SMEM_BYTES 19584   // ln1 is the max user: 17408 tile + 2048 red + 128

__device__ __forceinline__ float bf2f(ushort u) {
  union { uint i; float f; } v; v.i = ((uint)u) << 16; return v.f;
}
__device__ __forceinline__ ushort f2bf(float f) {
  union { float f; uint i; } v; v.f = f;
  uint u = v.i;
  return (ushort)((u + 0x7fffu + ((u >> 16) & 1u)) >> 16);
}

// 64x64 tile bf16 MFMA GEMM step: D = A[M][K] @ B[N][K]^T (K-contig rows).
// epi: 0=qkv(+bias, scale q) 1=proj(+bias+resid->f32)
//      2=fc1(+bias+gelu->bf16) 3=fc2(+bias[m]+resid[n*256+m]->f32 [C][N])
__device__ __forceinline__ void gemm_tile(
    const ushort* __restrict__ A, const ushort* __restrict__ B,
    const float* __restrict__ bias, const float* __restrict__ resid,
    ushort* __restrict__ outb, float* __restrict__ outf,
    int N, int K, int m0, int n0, int epi, char* smem)
{
  ushort* As = (ushort*)smem;          // [64][32]
  ushort* Bs = As + 64 * 32;           // [64][32]
  const int tid = threadIdx.x;
  const int lane = tid & 63;
  const int w = tid >> 6;

  floatx4 acc[4] = {{0.f,0.f,0.f,0.f},{0.f,0.f,0.f,0.f},
                    {0.f,0.f,0.f,0.f},{0.f,0.f,0.f,0.f}};

  const int srow = tid >> 2;
  const int scol = (tid & 3) * 8;
  const ushort* Ag = A + (size_t)(m0 + srow) * K + scol;
  const ushort* Bg = B + (size_t)(n0 + srow) * K + scol;
  ushort* Al = As + tid * 8;
  ushort* Bl = Bs + tid * 8;
  const int fm = lane & 15;
  const int fk = (lane >> 4) * 8;

  for (int kt = 0; kt < K; kt += 32) {
    __builtin_amdgcn_global_load_lds(AS1(Ag + kt), AS3(Al), 16, 0, 0);
    __builtin_amdgcn_global_load_lds(AS1(Bg + kt), AS3(Bl), 16, 0, 0);
    asm volatile("s_waitcnt vmcnt(0)" ::: "memory");
    __syncthreads();
    short8 af = *(const short8*)&As[(w * 16 + fm) * 32 + fk];
    #pragma unroll
    for (int nt = 0; nt < 4; ++nt) {
      short8 bfr = *(const short8*)&Bs[(nt * 16 + fm) * 32 + fk];
      acc[nt] = __builtin_amdgcn_mfma_f32_16x16x32_bf16(af, bfr, acc[nt], 0, 0, 0);
    }
    __syncthreads();
  }

  const int q4 = (lane >> 4) * 4;
  #pragma unroll
  for (int nt = 0; nt < 4; ++nt) {
    #pragma unroll
    for (int r = 0; r < 4; ++r) {
      int m = m0 + w * 16 + q4 + r;
      int n = n0 + nt * 16 + fm;
      float v = acc[nt][r];
      if (epi == 0) {
        v += bias[n];
        if (n < 256) v *= 0.17677669529663687f;   // 1/sqrt(32) on q
        outb[(size_t)m * N + n] = f2bf(v);
      } else if (epi == 1) {
        v += bias[n] + resid[(size_t)m * N + n];
        outf[(size_t)m * N + n] = v;
      } else if (epi == 2) {
        v += bias[n];
        v = 0.5f * v * (1.0f + erff(v * 0.70710678118654752f));
        outb[(size_t)m * N + n] = f2bf(v);
      } else {
        v += bias[m] + resid[(size_t)n * 256 + m];
        outf[(size_t)m * N + n] = v;   // final [C][N], coalesced in n
      }
    }
  }
}

__global__ __launch_bounds__(256, 2) void mega_kernel(
    const float* __restrict__ x,
    const float* __restrict__ n1w, const float* __restrict__ n1b,
    const float* __restrict__ qkvw, const float* __restrict__ qkvb,
    const float* __restrict__ projw, const float* __restrict__ projb,
    const float* __restrict__ n2w, const float* __restrict__ n2b,
    const float* __restrict__ f1w, const float* __restrict__ f1b,
    const float* __restrict__ f2w, const float* __restrict__ f2b,
    ushort* wcat, float* xT, ushort* t, ushort* qh, ushort* attnO,
    float* outf)
{
  __shared__ __align__(16) char smem[SMEM_BYTES];
  const int tid = threadIdx.x;
  const int bid = blockIdx.x;
  cg::grid_group grid = cg::this_grid();

  const ushort* qw_bf = wcat;
  const ushort* pw_bf = wcat + 196608;
  const ushort* f1_bf = wcat + 262144;
  const ushort* f2_bf = wcat + 524288;

  // ---- P0: weight fp32->bf16 cvt, then LN1 + transpose ----
  for (int idx = bid * 256 + tid; idx < 786432; idx += NBLK * 256) {
    float v;
    if (idx < 196608)       v = qkvw[idx];
    else if (idx < 262144)  v = projw[idx - 196608];
    else if (idx < 524288)  v = f1w[idx - 262144];
    else                    v = f2w[idx - 524288];
    wcat[idx] = f2bf(v);
  }
  {
    float* tile = (float*)smem;            // [256][17]
    float* red  = (float*)(smem + 17408);  // [2][16][16]
    float* mu   = (float*)(smem + 19456);  // [16]
    float* rsv  = (float*)(smem + 19520);  // [16]
    const int px = tid & 15, grp = tid >> 4;
    for (int tb = bid; tb < 196; tb += NBLK) {
      int n0 = tb * 16;
      #pragma unroll 4
      for (int it = 0; it < 16; ++it) {
        int c = it * 16 + grp;
        tile[c * 17 + px] = x[(size_t)c * 3136 + n0 + px];
      }
      __syncthreads();
      float s = 0.f, ss = 0.f;
      #pragma unroll
      for (int i = 0; i < 16; ++i) {
        float v = tile[(grp * 16 + i) * 17 + px];
        s += v; ss += v * v;
      }
      red[0 * 256 + px * 16 + grp] = s;
      red[1 * 256 + px * 16 + grp] = ss;
      __syncthreads();
      if (tid < 16) {
        float s2 = 0.f, ss2 = 0.f;
        #pragma unroll
        for (int g = 0; g < 16; ++g) {
          s2 += red[0 * 256 + tid * 16 + g];
          ss2 += red[1 * 256 + tid * 16 + g];
        }
        float m = s2 * (1.f / 256.f);
        float var = ss2 * (1.f / 256.f) - m * m;
        mu[tid] = m;
        rsv[tid] = rsqrtf(var + 1e-5f);
      }
      __syncthreads();
      const float wc = n1w[tid], bc = n1b[tid];
      #pragma unroll 4
      for (int p = 0; p < 16; ++p) {
        float v = tile[tid * 17 + p];
        xT[(size_t)(n0 + p) * 256 + tid] = v;
        t[(size_t)(n0 + p) * 256 + tid] = f2bf((v - mu[p]) * rsv[p] * wc + bc);
      }
      __syncthreads();   // protect tile reuse on next iteration
    }
  }
  grid.sync();

  // ---- P1: qkv = t[3136,256] @ qkv_w[768,256]^T ----
  for (int tt = bid; tt < 588; tt += NBLK)
    gemm_tile(t, qw_bf, qkvb, nullptr, qh, nullptr,
              768, 256, (tt / 12) * 64, (tt % 12) * 64, 0, smem);
  grid.sync();

  // ---- P2: local attention (all LDS traffic is intra-half-wave; no barriers)
  {
    float* qs = (float*)smem;          // [256]
    float* pr = (float*)(smem + 1024); // [8][64]
    const int h = tid >> 5, dd = tid & 31;
    for (int n = bid; n < 3136; n += NBLK) {
      const int i = n / 56, j = n % 56;
      qs[tid] = bf2f(qh[(size_t)n * 768 + tid]);
      float s0 = -1e30f, s1 = -1e30f;
      #pragma unroll
      for (int p = 0; p < 2; ++p) {
        int m = p * 32 + dd;
        float s = -1e30f;
        if (m < 49) {
          int ii = i + m / 7 - 3;
          int jj = j + m % 7 - 3;
          if (ii >= 0 && ii < 56 && jj >= 0 && jj < 56) {
            const ushort* kp = qh + (size_t)(ii * 56 + jj) * 768 + 256 + h * 32;
            float a = 0.f;
            #pragma unroll
            for (int u = 0; u < 4; ++u) {
              short8 kv = *(const short8*)(kp + u * 8);
              #pragma unroll
              for (int e = 0; e < 8; ++e)
                a += qs[h * 32 + u * 8 + e] * bf2f((ushort)kv[e]);
            }
            s = a;
          }
        }
        if (p == 0) s0 = s; else s1 = s;
      }
      float mx = fmaxf(s0, s1);
      #pragma unroll
      for (int o = 16; o >= 1; o >>= 1) mx = fmaxf(mx, __shfl_xor(mx, o));
      float e0 = __expf(s0 - mx);
      float e1 = __expf(s1 - mx);
      float sm = e0 + e1;
      #pragma unroll
      for (int o = 16; o >= 1; o >>= 1) sm += __shfl_xor(sm, o);
      float inv = 1.0f / sm;
      pr[h * 64 + dd] = e0 * inv;
      pr[h * 64 + dd + 32] = e1 * inv;

      float accv = 0.f;
      #pragma unroll
      for (int di = -3; di <= 3; ++di) {
        int ii = i + di;
        if (ii < 0 || ii >= 56) continue;
        #pragma unroll
        for (int dj = -3; dj <= 3; ++dj) {
          int jj = j + dj;
          if (jj < 0 || jj >= 56) continue;
          int m = (di + 3) * 7 + (dj + 3);
          float pm = pr[h * 64 + m];
          float vv = bf2f(qh[(size_t)(ii * 56 + jj) * 768 + 512 + tid]);
          accv += pm * vv;
        }
      }
      attnO[(size_t)n * 256 + tid] = f2bf(accv);
    }
  }
  grid.sync();

  // ---- P3: x1 = attnO @ proj_w^T + bias + xT  (fp32, in-place over xT) ----
  for (int tt = bid; tt < 196; tt += NBLK)
    gemm_tile(attnO, pw_bf, projb, xT, nullptr, xT,
              256, 256, (tt / 4) * 64, (tt % 4) * 64, 1, smem);
  grid.sync();

  // ---- P4: LN2 (rows contiguous; one wave per row, 4 rows/block-group) ----
  for (int rg = bid; rg < 784; rg += NBLK) {
    const int row = rg * 4 + (tid >> 6);
    const int lane = tid & 63;
    floatx4 v = *(const floatx4*)(xT + (size_t)row * 256 + lane * 4);
    float s = v[0] + v[1] + v[2] + v[3];
    float ss = v[0]*v[0] + v[1]*v[1] + v[2]*v[2] + v[3]*v[3];
    #pragma unroll
    for (int o = 32; o >= 1; o >>= 1) { s += __shfl_xor(s, o); ss += __shfl_xor(ss, o); }
    float m = s * (1.f / 256.f);
    float var = ss * (1.f / 256.f) - m * m;
    float rs = rsqrtf(var + 1e-5f);
    ushort4v o4;
    #pragma unroll
    for (int e = 0; e < 4; ++e) {
      int c = lane * 4 + e;
      o4[e] = f2bf((v[e] - m) * rs * n2w[c] + n2b[c]);
    }
    *(ushort4v*)(t + (size_t)row * 256 + lane * 4) = o4;
  }
  grid.sync();

  // ---- P5: h1 = gelu(t2 @ fc1_w^T + b) ----
  for (int tt = bid; tt < 784; tt += NBLK)
    gemm_tile(t, f1_bf, f1b, nullptr, qh, nullptr,
              1024, 256, (tt / 16) * 64, (tt % 16) * 64, 2, smem);
  grid.sync();

  // ---- P6: out[C][N] = fc2_w[256,1024] @ h1[3136,1024]^T + b + x1^T ----
  for (int tt = bid; tt < 196; tt += NBLK)
    gemm_tile(f2_bf, qh, f2b, xT, nullptr, outf,
              3136, 1024, (tt % 4) * 64, (tt / 4) * 64, 3, smem);
}

// ---------------------------------------------------------------------------
extern "C" void kernel_launch(void* const* d_in, const int* in_sizes, int n_in,
                              void* d_out, int out_size, void* d_ws, size_t ws_size,
                              hipStream_t stream) {
  const float* x     = (const float*)d_in[0];
  const float* n1w   = (const float*)d_in[1];
  const float* n1b   = (const float*)d_in[2];
  const float* qkvw  = (const float*)d_in[3];
  const float* qkvb  = (const float*)d_in[4];
  const float* projw = (const float*)d_in[5];
  const float* projb = (const float*)d_in[6];
  const float* n2w   = (const float*)d_in[7];
  const float* n2b   = (const float*)d_in[8];
  const float* f1w   = (const float*)d_in[9];
  const float* f1b   = (const float*)d_in[10];
  const float* f2w   = (const float*)d_in[11];
  const float* f2b   = (const float*)d_in[12];

  char* ws = (char*)d_ws;
  ushort* wcat = (ushort*)(ws + 0);            // 786432 bf16
  float*  xT   = (float*)(ws + 1572864);       // 802816 f32 (xT then x1)
  ushort* t    = (ushort*)(ws + 4784128);      // 802816 bf16 (t1 then t2)
  ushort* qh   = (ushort*)(ws + 6389760);      // qkv [3136][768] then h1 [3136][1024]
  ushort* attnO= (ushort*)(ws + 12812288);     // 802816 bf16
  float* outf  = (float*)d_out;

  void* args[] = {
    (void*)&x, (void*)&n1w, (void*)&n1b, (void*)&qkvw, (void*)&qkvb,
    (void*)&projw, (void*)&projb, (void*)&n2w, (void*)&n2b,
    (void*)&f1w, (void*)&f1b, (void*)&f2w, (void*)&f2b,
    (void*)&wcat, (void*)&xT, (void*)&t, (void*)&qh, (void*)&attnO,
    (void*)&outf
  };
  hipLaunchCooperativeKernel((const void*)mega_kernel, dim3(NBLK), dim3(256),
                             args, 0, stream);
}

// Round 3
// 224.350 us; speedup vs baseline: 2.5305x; 2.5305x over previous
//
#include <hip/hip_runtime.h>
#include <math.h>

// ---------------------------------------------------------------------------
// LocalTransformerBlock2d: B=1, C=256, H=W=56 (N=3136), 8 heads x d=32,
// 7x7 local window. fp32 in/out; bf16 MFMA GEMMs.
// 3 kernels (grid.sync measured at ~75us/sync on gfx950 -- never again):
//   K1 prep: weight fp32->bf16 cvt + LN1(+transpose)        [3268 blk x 256]
//   K2 qkv GEMM 64x64 MFMA tiles                            [588 blk x 256]
//   K3 mega: per-16-pixel block: attn -> proj+resid+LN2 ->
//            fc1+gelu -> fc2+resid, intermediates in LDS    [196 blk x 512]
// ---------------------------------------------------------------------------

typedef unsigned int uint;
typedef unsigned short ushort;
typedef __attribute__((ext_vector_type(8))) short short8;   // 8 bf16
typedef __attribute__((ext_vector_type(4))) float floatx4;  // MFMA acc
typedef __attribute__((ext_vector_type(4))) unsigned short ushort4v;

#define AS1(p) (const __attribute__((address_space(1))) void*)(p)
#define AS3(p) (__attribute__((address_space(3))) void*)(p)

__device__ __forceinline__ float bf2f(ushort u) {
  union { uint i; float f; } v; v.i = ((uint)u) << 16; return v.f;
}
__device__ __forceinline__ ushort f2bf(float f) {
  union { float f; uint i; } v; v.f = f;
  uint u = v.i;
  return (ushort)((u + 0x7fffu + ((u >> 16) & 1u)) >> 16);
}

// ---------------------------------------------------------------------------
// K1: blocks 0..195 do LN1+transpose (16 px each); blocks 196+ do weight cvt.
// ---------------------------------------------------------------------------
__global__ __launch_bounds__(256) void prep_kernel(
    const float* __restrict__ x, const float* __restrict__ n1w,
    const float* __restrict__ n1b,
    const float* __restrict__ qkvw, const float* __restrict__ projw,
    const float* __restrict__ f1w, const float* __restrict__ f2w,
    float* __restrict__ xT, ushort* __restrict__ t1, ushort* __restrict__ wcat)
{
  const int tid = threadIdx.x;
  const int bid = blockIdx.x;
  if (bid >= 196) {
    int idx = (bid - 196) * 256 + tid;
    float v;
    if (idx < 196608)       v = qkvw[idx];
    else if (idx < 262144)  v = projw[idx - 196608];
    else if (idx < 524288)  v = f1w[idx - 262144];
    else                    v = f2w[idx - 524288];
    wcat[idx] = f2bf(v);
    return;
  }
  __shared__ float tile[256 * 17];
  __shared__ float red[2][16][16];
  __shared__ float mu[16], rsv[16];
  const int n0 = bid * 16;
  const int px = tid & 15, grp = tid >> 4;
  #pragma unroll 4
  for (int it = 0; it < 16; ++it) {
    int c = it * 16 + grp;
    tile[c * 17 + px] = x[(size_t)c * 3136 + n0 + px];
  }
  __syncthreads();
  float s = 0.f, ss = 0.f;
  #pragma unroll
  for (int i = 0; i < 16; ++i) {
    float v = tile[(grp * 16 + i) * 17 + px];
    s += v; ss += v * v;
  }
  red[0][px][grp] = s; red[1][px][grp] = ss;
  __syncthreads();
  if (tid < 16) {
    float s2 = 0.f, ss2 = 0.f;
    #pragma unroll
    for (int g = 0; g < 16; ++g) { s2 += red[0][tid][g]; ss2 += red[1][tid][g]; }
    float m = s2 * (1.f / 256.f);
    float var = ss2 * (1.f / 256.f) - m * m;
    mu[tid] = m;
    rsv[tid] = rsqrtf(var + 1e-5f);
  }
  __syncthreads();
  const float wc = n1w[tid], bc = n1b[tid];
  #pragma unroll 4
  for (int p = 0; p < 16; ++p) {
    float v = tile[tid * 17 + p];
    xT[(size_t)(n0 + p) * 256 + tid] = v;
    t1[(size_t)(n0 + p) * 256 + tid] = f2bf((v - mu[p]) * rsv[p] * wc + bc);
  }
}

// ---------------------------------------------------------------------------
// K2: qkv = t1[3136,256] @ qkv_w[768,256]^T + bias (q pre-scaled by 1/sqrt(32))
// 64x64 tile, BK=32, 4 waves. (R1-verified structure.)
// ---------------------------------------------------------------------------
__global__ __launch_bounds__(256) void qkv_kernel(
    const ushort* __restrict__ A, const ushort* __restrict__ B,
    const float* __restrict__ bias, ushort* __restrict__ out)
{
  __shared__ ushort As[64 * 32];
  __shared__ ushort Bs[64 * 32];
  const int tid = threadIdx.x;
  const int lane = tid & 63;
  const int w = tid >> 6;
  const int m0 = blockIdx.y * 64;
  const int n0 = blockIdx.x * 64;

  floatx4 acc[4] = {{0.f,0.f,0.f,0.f},{0.f,0.f,0.f,0.f},
                    {0.f,0.f,0.f,0.f},{0.f,0.f,0.f,0.f}};
  const int srow = tid >> 2;
  const int scol = (tid & 3) * 8;
  const ushort* Ag = A + (size_t)(m0 + srow) * 256 + scol;
  const ushort* Bg = B + (size_t)(n0 + srow) * 256 + scol;
  ushort* Al = As + tid * 8;
  ushort* Bl = Bs + tid * 8;
  const int fm = lane & 15;
  const int fk = (lane >> 4) * 8;

  for (int kt = 0; kt < 256; kt += 32) {
    __builtin_amdgcn_global_load_lds(AS1(Ag + kt), AS3(Al), 16, 0, 0);
    __builtin_amdgcn_global_load_lds(AS1(Bg + kt), AS3(Bl), 16, 0, 0);
    asm volatile("s_waitcnt vmcnt(0)" ::: "memory");
    __syncthreads();
    short8 af = *(const short8*)&As[(w * 16 + fm) * 32 + fk];
    #pragma unroll
    for (int nt = 0; nt < 4; ++nt) {
      short8 bfr = *(const short8*)&Bs[(nt * 16 + fm) * 32 + fk];
      acc[nt] = __builtin_amdgcn_mfma_f32_16x16x32_bf16(af, bfr, acc[nt], 0, 0, 0);
    }
    __syncthreads();
  }
  const int q4 = (lane >> 4) * 4;
  #pragma unroll
  for (int nt = 0; nt < 4; ++nt) {
    #pragma unroll
    for (int r = 0; r < 4; ++r) {
      int m = m0 + w * 16 + q4 + r;
      int n = n0 + nt * 16 + fm;
      float v = acc[nt][r] + bias[n];
      if (n < 256) v *= 0.17677669529663687f;
      out[(size_t)m * 768 + n] = f2bf(v);
    }
  }
}

// ---------------------------------------------------------------------------
// K3: mega. Block = 16 consecutive pixels, 512 threads (8 waves).
// LDS layout (bytes):
//  Bs0 0..16384 | Bs1 16384..32768 | x1s 32768..49152 (f32[16][256])
//  t2s 49152 (bf16[16][264]) | aas 57600 (bf16[16][264]) | h1s 66048 (bf16[16][1032])
//  qs 99072 (f32[2][256]) | pr 101120 (f32[2][8][64]) | red 105216 | stats 106240
// ---------------------------------------------------------------------------
#define MEGA_SMEM 106368

__global__ __launch_bounds__(512, 1) void mega_kernel(
    const ushort* __restrict__ qh, const float* __restrict__ xT,
    const ushort* __restrict__ pw_bf, const float* __restrict__ projb,
    const float* __restrict__ n2w, const float* __restrict__ n2b,
    const ushort* __restrict__ f1_bf, const float* __restrict__ f1b,
    const ushort* __restrict__ f2_bf, const float* __restrict__ f2b,
    float* __restrict__ outf)
{
  __shared__ __align__(16) char smem[MEGA_SMEM];
  ushort* Bs0  = (ushort*)(smem);
  ushort* Bs1  = (ushort*)(smem + 16384);
  float*  x1s  = (float*)(smem + 32768);
  ushort* t2s  = (ushort*)(smem + 49152);
  ushort* aas  = (ushort*)(smem + 57600);
  ushort* h1s  = (ushort*)(smem + 66048);
  float*  qs   = (float*)(smem + 99072);
  float*  pr   = (float*)(smem + 101120);
  float*  red  = (float*)(smem + 105216);
  float*  stats= (float*)(smem + 106240);

  const int tid = threadIdx.x;
  const int bid = blockIdx.x;
  const int n0 = bid * 16;
  const int lane = tid & 63;
  const int w = tid >> 6;
  const int fm = lane & 15;
  const int fk8 = (lane >> 4) * 8;
  const int q4 = (lane >> 4) * 4;

  // ---- attention for 16 pixels (2 at a time; all LDS traffic half-wave-local)
  {
    const int sub = tid >> 8;          // 0/1: which pixel of the pair
    const int t8 = tid & 255;
    const int h = t8 >> 5, dd = t8 & 31;
    #pragma unroll 2
    for (int it = 0; it < 8; ++it) {
      const int p = it * 2 + sub;
      const int n = n0 + p;
      const int i = n / 56, j = n % 56;
      qs[sub * 256 + t8] = bf2f(qh[(size_t)n * 768 + t8]);
      float s0 = -1e30f, s1 = -1e30f;
      #pragma unroll
      for (int pp = 0; pp < 2; ++pp) {
        int m = pp * 32 + dd;
        float s = -1e30f;
        if (m < 49) {
          int ii = i + m / 7 - 3;
          int jj = j + m % 7 - 3;
          if (ii >= 0 && ii < 56 && jj >= 0 && jj < 56) {
            const ushort* kp = qh + (size_t)(ii * 56 + jj) * 768 + 256 + h * 32;
            float a = 0.f;
            #pragma unroll
            for (int u = 0; u < 4; ++u) {
              short8 kv = *(const short8*)(kp + u * 8);
              #pragma unroll
              for (int e = 0; e < 8; ++e)
                a += qs[sub * 256 + h * 32 + u * 8 + e] * bf2f((ushort)kv[e]);
            }
            s = a;
          }
        }
        if (pp == 0) s0 = s; else s1 = s;
      }
      float mx = fmaxf(s0, s1);
      #pragma unroll
      for (int o = 16; o >= 1; o >>= 1) mx = fmaxf(mx, __shfl_xor(mx, o));
      float e0 = __expf(s0 - mx);
      float e1 = __expf(s1 - mx);
      float sm = e0 + e1;
      #pragma unroll
      for (int o = 16; o >= 1; o >>= 1) sm += __shfl_xor(sm, o);
      float inv = 1.0f / sm;
      pr[sub * 512 + h * 64 + dd] = e0 * inv;
      pr[sub * 512 + h * 64 + dd + 32] = e1 * inv;

      float accv = 0.f;
      #pragma unroll
      for (int di = -3; di <= 3; ++di) {
        int ii = i + di;
        if (ii < 0 || ii >= 56) continue;
        #pragma unroll
        for (int dj = -3; dj <= 3; ++dj) {
          int jj = j + dj;
          if (jj < 0 || jj >= 56) continue;
          int m = (di + 3) * 7 + (dj + 3);
          float pm = pr[sub * 512 + h * 64 + m];
          float vv = bf2f(qh[(size_t)(ii * 56 + jj) * 768 + 512 + t8]);
          accv += pm * vv;
        }
      }
      aas[p * 264 + t8] = f2bf(accv);
    }
  }
  __syncthreads();

  // B-tile stage: 256 rows x 32 k (16 KB) via global_load_lds, 16 B/thread x2
#define STAGE(buf, Bg, stride, kt) do { \
    const ushort* _g0 = (Bg) + (size_t)(tid >> 2) * (stride) + (kt) + (tid & 3) * 8; \
    const ushort* _g1 = (Bg) + (size_t)(128 + (tid >> 2)) * (stride) + (kt) + (tid & 3) * 8; \
    __builtin_amdgcn_global_load_lds(AS1(_g0), AS3((buf) + tid * 8), 16, 0, 0); \
    __builtin_amdgcn_global_load_lds(AS1(_g1), AS3((buf) + 4096 + tid * 8), 16, 0, 0); \
  } while (0)

  floatx4 acc[2];

  // ---- proj: x1 = aas[16,256] @ projW^T + b + xT ; fused LN2 -> t2s
  acc[0] = (floatx4){0.f,0.f,0.f,0.f};
  acc[1] = (floatx4){0.f,0.f,0.f,0.f};
  STAGE(Bs0, pw_bf, 256, 0);
  for (int it = 0; it < 8; ++it) {
    ushort* cur = (it & 1) ? Bs1 : Bs0;
    ushort* nxt = (it & 1) ? Bs0 : Bs1;
    if (it < 7) {
      STAGE(nxt, pw_bf, 256, (it + 1) * 32);
      asm volatile("s_waitcnt vmcnt(2)" ::: "memory");
    } else {
      asm volatile("s_waitcnt vmcnt(0)" ::: "memory");
    }
    __syncthreads();
    short8 af = *(const short8*)&aas[fm * 264 + it * 32 + fk8];
    #pragma unroll
    for (int nt = 0; nt < 2; ++nt) {
      short8 bfr = *(const short8*)&cur[(w * 32 + nt * 16 + fm) * 32 + fk8];
      acc[nt] = __builtin_amdgcn_mfma_f32_16x16x32_bf16(af, bfr, acc[nt], 0, 0, 0);
    }
    __syncthreads();
  }
  // epilogue: +bias +resid, keep x1 in LDS, rowwise stats for LN2
  #pragma unroll
  for (int r = 0; r < 4; ++r) {
    int m = q4 + r;
    float vs = 0.f, vss = 0.f;
    #pragma unroll
    for (int nt = 0; nt < 2; ++nt) {
      int n = w * 32 + nt * 16 + fm;
      float v = acc[nt][r] + projb[n] + xT[(size_t)(n0 + m) * 256 + n];
      x1s[m * 256 + n] = v;
      acc[nt][r] = v;
      vs += v; vss += v * v;
    }
    #pragma unroll
    for (int o = 8; o >= 1; o >>= 1) { vs += __shfl_xor(vs, o); vss += __shfl_xor(vss, o); }
    if (fm == 0) { red[(w * 16 + m) * 2] = vs; red[(w * 16 + m) * 2 + 1] = vss; }
  }
  __syncthreads();
  if (tid < 16) {
    float s2 = 0.f, ss2 = 0.f;
    #pragma unroll
    for (int w8 = 0; w8 < 8; ++w8) {
      s2 += red[(w8 * 16 + tid) * 2];
      ss2 += red[(w8 * 16 + tid) * 2 + 1];
    }
    float m = s2 * (1.f / 256.f);
    float var = ss2 * (1.f / 256.f) - m * m;
    stats[tid * 2] = m;
    stats[tid * 2 + 1] = rsqrtf(var + 1e-5f);
  }
  __syncthreads();
  #pragma unroll
  for (int r = 0; r < 4; ++r) {
    int m = q4 + r;
    float mu = stats[m * 2], rs = stats[m * 2 + 1];
    #pragma unroll
    for (int nt = 0; nt < 2; ++nt) {
      int n = w * 32 + nt * 16 + fm;
      t2s[m * 264 + n] = f2bf((acc[nt][r] - mu) * rs * n2w[n] + n2b[n]);
    }
  }
  __syncthreads();

  // ---- fc1: h1 = gelu(t2s[16,256] @ f1w^T + b), 4 chunks of 256 cols
  for (int nc = 0; nc < 4; ++nc) {
    acc[0] = (floatx4){0.f,0.f,0.f,0.f};
    acc[1] = (floatx4){0.f,0.f,0.f,0.f};
    const ushort* Bg = f1_bf + (size_t)nc * 256 * 256;
    STAGE(Bs0, Bg, 256, 0);
    for (int it = 0; it < 8; ++it) {
      ushort* cur = (it & 1) ? Bs1 : Bs0;
      ushort* nxt = (it & 1) ? Bs0 : Bs1;
      if (it < 7) {
        STAGE(nxt, Bg, 256, (it + 1) * 32);
        asm volatile("s_waitcnt vmcnt(2)" ::: "memory");
      } else {
        asm volatile("s_waitcnt vmcnt(0)" ::: "memory");
      }
      __syncthreads();
      short8 af = *(const short8*)&t2s[fm * 264 + it * 32 + fk8];
      #pragma unroll
      for (int nt = 0; nt < 2; ++nt) {
        short8 bfr = *(const short8*)&cur[(w * 32 + nt * 16 + fm) * 32 + fk8];
        acc[nt] = __builtin_amdgcn_mfma_f32_16x16x32_bf16(af, bfr, acc[nt], 0, 0, 0);
      }
      __syncthreads();
    }
    #pragma unroll
    for (int r = 0; r < 4; ++r) {
      int m = q4 + r;
      #pragma unroll
      for (int nt = 0; nt < 2; ++nt) {
        int nl = w * 32 + nt * 16 + fm;
        int n = nc * 256 + nl;
        float v = acc[nt][r] + f1b[n];
        v = 0.5f * v * (1.0f + erff(v * 0.70710678118654752f));
        h1s[m * 1032 + n] = f2bf(v);
      }
    }
  }
  __syncthreads();

  // ---- fc2: out = h1s[16,1024] @ f2w^T + b + x1s, store [C][N] layout
  acc[0] = (floatx4){0.f,0.f,0.f,0.f};
  acc[1] = (floatx4){0.f,0.f,0.f,0.f};
  STAGE(Bs0, f2_bf, 1024, 0);
  for (int it = 0; it < 32; ++it) {
    ushort* cur = (it & 1) ? Bs1 : Bs0;
    ushort* nxt = (it & 1) ? Bs0 : Bs1;
    if (it < 31) {
      STAGE(nxt, f2_bf, 1024, (it + 1) * 32);
      asm volatile("s_waitcnt vmcnt(2)" ::: "memory");
    } else {
      asm volatile("s_waitcnt vmcnt(0)" ::: "memory");
    }
    __syncthreads();
    short8 af = *(const short8*)&h1s[fm * 1032 + it * 32 + fk8];
    #pragma unroll
    for (int nt = 0; nt < 2; ++nt) {
      short8 bfr = *(const short8*)&cur[(w * 32 + nt * 16 + fm) * 32 + fk8];
      acc[nt] = __builtin_amdgcn_mfma_f32_16x16x32_bf16(af, bfr, acc[nt], 0, 0, 0);
    }
    __syncthreads();
  }
  #pragma unroll
  for (int r = 0; r < 4; ++r) {
    int m = q4 + r;
    #pragma unroll
    for (int nt = 0; nt < 2; ++nt) {
      int n = w * 32 + nt * 16 + fm;
      float v = acc[nt][r] + f2b[n] + x1s[m * 256 + n];
      outf[(size_t)n * 3136 + n0 + m] = v;
    }
  }
#undef STAGE
}

// ---------------------------------------------------------------------------
extern "C" void kernel_launch(void* const* d_in, const int* in_sizes, int n_in,
                              void* d_out, int out_size, void* d_ws, size_t ws_size,
                              hipStream_t stream) {
  const float* x     = (const float*)d_in[0];
  const float* n1w   = (const float*)d_in[1];
  const float* n1b   = (const float*)d_in[2];
  const float* qkvw  = (const float*)d_in[3];
  const float* qkvb  = (const float*)d_in[4];
  const float* projw = (const float*)d_in[5];
  const float* projb = (const float*)d_in[6];
  const float* n2w   = (const float*)d_in[7];
  const float* n2b   = (const float*)d_in[8];
  const float* f1w   = (const float*)d_in[9];
  const float* f1b   = (const float*)d_in[10];
  const float* f2w   = (const float*)d_in[11];
  const float* f2b   = (const float*)d_in[12];

  char* ws = (char*)d_ws;
  ushort* wcat = (ushort*)(ws + 0);            // 786432 bf16
  float*  xT   = (float*)(ws + 1572864);       // 802816 f32
  ushort* t1   = (ushort*)(ws + 4784128);      // 802816 bf16
  ushort* qh   = (ushort*)(ws + 6389760);      // qkv [3136][768] bf16

  const ushort* qw_bf = wcat;
  const ushort* pw_bf = wcat + 196608;
  const ushort* f1_bf = wcat + 262144;
  const ushort* f2_bf = wcat + 524288;
  float* outf = (float*)d_out;

  hipLaunchKernelGGL(prep_kernel, dim3(3268), dim3(256), 0, stream,
                     x, n1w, n1b, qkvw, projw, f1w, f2w, xT, t1, wcat);
  hipLaunchKernelGGL(qkv_kernel, dim3(12, 49), dim3(256), 0, stream,
                     t1, qw_bf, qkvb, qh);
  hipLaunchKernelGGL(mega_kernel, dim3(196), dim3(512), 0, stream,
                     qh, xT, pw_bf, projb, n2w, n2b,
                     f1_bf, f1b, f2_bf, f2b, outf);
}

// Round 4
// 154.231 us; speedup vs baseline: 3.6809x; 1.4546x over previous
//
#include <hip/hip_runtime.h>
#include <math.h>

// ---------------------------------------------------------------------------
// LocalTransformerBlock2d: B=1, C=256, H=W=56 (N=3136), 8 heads x d=32,
// 7x7 local window. fp32 in/out; bf16 MFMA GEMMs.
// 7 stream-ordered kernels, high block counts (R3's fused 196-block kernel
// was latency-bound: 1 blk/CU, serial chains; grid.sync ~75us -- both dead ends):
//   prep(cvt+LN1T) -> qkv -> attn -> proj(+resid) -> LN2 -> fc1(+gelu) -> fc2(+resid)
// GEMMs: K=256 fully LDS-resident (64KB, 2 blk/CU), ONE barrier per K-pass,
// XOR-swizzled LDS (col_block ^= row&7) => conflict-free ds_read_b128.
// ---------------------------------------------------------------------------

typedef unsigned int uint;
typedef unsigned short ushort;
typedef __attribute__((ext_vector_type(8))) short short8;   // 8 bf16
typedef __attribute__((ext_vector_type(4))) float floatx4;  // MFMA acc
typedef __attribute__((ext_vector_type(4))) unsigned short ushort4v;

#define AS1(p) (const __attribute__((address_space(1))) void*)(p)
#define AS3(p) (__attribute__((address_space(3))) void*)(p)

__device__ __forceinline__ float bf2f(ushort u) {
  union { uint i; float f; } v; v.i = ((uint)u) << 16; return v.f;
}
__device__ __forceinline__ ushort f2bf(float f) {
  union { float f; uint i; } v; v.f = f;
  uint u = v.i;
  return (ushort)((u + 0x7fffu + ((u >> 16) & 1u)) >> 16);
}

// Stage a 64-row x 256-col bf16 panel into LDS with XOR swizzle.
// src must point at (row0, kOff). LDS slot (tid&31) of row (tid>>5)+8r holds
// global col-block ((tid&31) ^ (row&7)); row&7 is invariant across rounds.
__device__ __forceinline__ void stage64(const ushort* src, int kstride,
                                        ushort* dstBase, int tid) {
  const int srow = tid >> 5;                 // 0..7
  const int scb  = (tid & 31) ^ srow;        // permuted 16B block
  const ushort* g = src + (size_t)srow * kstride + scb * 8;
  ushort* d = dstBase + tid * 8;             // wave-uniform base + lane*16B
  #pragma unroll
  for (int r = 0; r < 8; ++r) {
    __builtin_amdgcn_global_load_lds(AS1(g), AS3(d), 16, 0, 0);
    g += 8 * kstride;
    d += 2048;
  }
}

// 8 k-iters over the resident K=256 panels; 4 n-subtiles per wave.
__device__ __forceinline__ void compute64(const ushort* As, const ushort* Bs,
                                          int w, int lane, floatx4 acc[4]) {
  const int fm = lane & 15;
  const int q  = lane >> 4;
  const int swz = fm & 7;
  const int arow = (w * 16 + fm) * 256;
  #pragma unroll
  for (int kt = 0; kt < 8; ++kt) {
    const int blk = ((kt * 4 + q) ^ swz) * 8;
    short8 af = *(const short8*)&As[arow + blk];
    #pragma unroll
    for (int nt = 0; nt < 4; ++nt) {
      short8 bfr = *(const short8*)&Bs[(nt * 16 + fm) * 256 + blk];
      acc[nt] = __builtin_amdgcn_mfma_f32_16x16x32_bf16(af, bfr, acc[nt], 0, 0, 0);
    }
  }
}

// ---------------------------------------------------------------------------
// prep: blocks 0..195 LN1+transpose (16 px each); blocks 196+ weight cvt.
// ---------------------------------------------------------------------------
__global__ __launch_bounds__(256) void prep_kernel(
    const float* __restrict__ x, const float* __restrict__ n1w,
    const float* __restrict__ n1b,
    const float* __restrict__ qkvw, const float* __restrict__ projw,
    const float* __restrict__ f1w, const float* __restrict__ f2w,
    float* __restrict__ xT, ushort* __restrict__ t1, ushort* __restrict__ wcat)
{
  const int tid = threadIdx.x;
  const int bid = blockIdx.x;
  if (bid >= 196) {
    int idx = (bid - 196) * 256 + tid;
    float v;
    if (idx < 196608)       v = qkvw[idx];
    else if (idx < 262144)  v = projw[idx - 196608];
    else if (idx < 524288)  v = f1w[idx - 262144];
    else                    v = f2w[idx - 524288];
    wcat[idx] = f2bf(v);
    return;
  }
  __shared__ float tile[256 * 17];
  __shared__ float red[2][16][16];
  __shared__ float mu[16], rsv[16];
  const int n0 = bid * 16;
  const int px = tid & 15, grp = tid >> 4;
  #pragma unroll 4
  for (int it = 0; it < 16; ++it) {
    int c = it * 16 + grp;
    tile[c * 17 + px] = x[(size_t)c * 3136 + n0 + px];
  }
  __syncthreads();
  float s = 0.f, ss = 0.f;
  #pragma unroll
  for (int i = 0; i < 16; ++i) {
    float v = tile[(grp * 16 + i) * 17 + px];
    s += v; ss += v * v;
  }
  red[0][px][grp] = s; red[1][px][grp] = ss;
  __syncthreads();
  if (tid < 16) {
    float s2 = 0.f, ss2 = 0.f;
    #pragma unroll
    for (int g = 0; g < 16; ++g) { s2 += red[0][tid][g]; ss2 += red[1][tid][g]; }
    float m = s2 * (1.f / 256.f);
    float var = ss2 * (1.f / 256.f) - m * m;
    mu[tid] = m;
    rsv[tid] = rsqrtf(var + 1e-5f);
  }
  __syncthreads();
  const float wc = n1w[tid], bc = n1b[tid];
  #pragma unroll 4
  for (int p = 0; p < 16; ++p) {
    float v = tile[tid * 17 + p];
    xT[(size_t)(n0 + p) * 256 + tid] = v;
    t1[(size_t)(n0 + p) * 256 + tid] = f2bf((v - mu[p]) * rsv[p] * wc + bc);
  }
}

// ---------------------------------------------------------------------------
// qkv: [3136,256] @ [768,256]^T + bias (q scaled). grid (12,49).
// ---------------------------------------------------------------------------
__global__ __launch_bounds__(256, 2) void qkv_kernel(
    const ushort* __restrict__ A, const ushort* __restrict__ B,
    const float* __restrict__ bias, ushort* __restrict__ out)
{
  __shared__ ushort As[16384], Bs[16384];
  const int tid = threadIdx.x, lane = tid & 63, w = tid >> 6;
  const int m0 = blockIdx.y * 64, n0 = blockIdx.x * 64;
  floatx4 acc[4] = {{0.f,0.f,0.f,0.f},{0.f,0.f,0.f,0.f},
                    {0.f,0.f,0.f,0.f},{0.f,0.f,0.f,0.f}};
  stage64(A + (size_t)m0 * 256, 256, As, tid);
  stage64(B + (size_t)n0 * 256, 256, Bs, tid);
  asm volatile("s_waitcnt vmcnt(0)" ::: "memory");
  __syncthreads();
  compute64(As, Bs, w, lane, acc);
  const int fm = lane & 15, q4 = (lane >> 4) * 4;
  #pragma unroll
  for (int nt = 0; nt < 4; ++nt)
    #pragma unroll
    for (int r = 0; r < 4; ++r) {
      int m = m0 + w * 16 + q4 + r;
      int n = n0 + nt * 16 + fm;
      float v = acc[nt][r] + bias[n];
      if (n < 256) v *= 0.17677669529663687f;   // 1/sqrt(32) on q
      out[(size_t)m * 768 + n] = f2bf(v);
    }
}

// ---------------------------------------------------------------------------
// attn: 1 px/block, 256 thr = 8 heads x 32. All LDS traffic half-wave-local.
// ---------------------------------------------------------------------------
__global__ __launch_bounds__(256) void attn_kernel(
    const ushort* __restrict__ qkv, ushort* __restrict__ out)
{
  const int n = blockIdx.x;
  const int i = n / 56, j = n % 56;
  const int tid = threadIdx.x;
  const int h = tid >> 5, dd = tid & 31;
  __shared__ float qs[256];
  __shared__ float pr[8][64];

  qs[tid] = bf2f(qkv[(size_t)n * 768 + tid]);
  float s0 = -1e30f, s1 = -1e30f;
  #pragma unroll
  for (int p = 0; p < 2; ++p) {
    int m = p * 32 + dd;
    float s = -1e30f;
    if (m < 49) {
      int ii = i + m / 7 - 3;
      int jj = j + m % 7 - 3;
      if (ii >= 0 && ii < 56 && jj >= 0 && jj < 56) {
        const ushort* kp = qkv + (size_t)(ii * 56 + jj) * 768 + 256 + h * 32;
        float a = 0.f;
        #pragma unroll
        for (int u = 0; u < 4; ++u) {
          short8 kv = *(const short8*)(kp + u * 8);
          #pragma unroll
          for (int e = 0; e < 8; ++e)
            a += qs[h * 32 + u * 8 + e] * bf2f((ushort)kv[e]);
        }
        s = a;
      }
    }
    if (p == 0) s0 = s; else s1 = s;
  }
  float mx = fmaxf(s0, s1);
  #pragma unroll
  for (int o = 16; o >= 1; o >>= 1) mx = fmaxf(mx, __shfl_xor(mx, o));
  float e0 = __expf(s0 - mx);
  float e1 = __expf(s1 - mx);
  float sm = e0 + e1;
  #pragma unroll
  for (int o = 16; o >= 1; o >>= 1) sm += __shfl_xor(sm, o);
  float inv = 1.0f / sm;
  pr[h][dd] = e0 * inv;
  pr[h][dd + 32] = e1 * inv;

  float accv = 0.f;
  #pragma unroll
  for (int di = -3; di <= 3; ++di) {
    int ii = i + di;
    if (ii < 0 || ii >= 56) continue;
    #pragma unroll
    for (int dj = -3; dj <= 3; ++dj) {
      int jj = j + dj;
      if (jj < 0 || jj >= 56) continue;
      int m = (di + 3) * 7 + (dj + 3);
      float pm = pr[h][m];
      float vv = bf2f(qkv[(size_t)(ii * 56 + jj) * 768 + 512 + tid]);
      accv += pm * vv;
    }
  }
  out[(size_t)n * 256 + tid] = f2bf(accv);
}

// ---------------------------------------------------------------------------
// proj: [3136,256] @ [256,256]^T + bias + resid -> x1 fp32. grid (4,49).
// ---------------------------------------------------------------------------
__global__ __launch_bounds__(256, 2) void proj_kernel(
    const ushort* __restrict__ A, const ushort* __restrict__ B,
    const float* __restrict__ bias, const float* __restrict__ resid,
    float* __restrict__ x1)
{
  __shared__ ushort As[16384], Bs[16384];
  const int tid = threadIdx.x, lane = tid & 63, w = tid >> 6;
  const int m0 = blockIdx.y * 64, n0 = blockIdx.x * 64;
  floatx4 acc[4] = {{0.f,0.f,0.f,0.f},{0.f,0.f,0.f,0.f},
                    {0.f,0.f,0.f,0.f},{0.f,0.f,0.f,0.f}};
  stage64(A + (size_t)m0 * 256, 256, As, tid);
  stage64(B + (size_t)n0 * 256, 256, Bs, tid);
  asm volatile("s_waitcnt vmcnt(0)" ::: "memory");
  __syncthreads();
  compute64(As, Bs, w, lane, acc);
  const int fm = lane & 15, q4 = (lane >> 4) * 4;
  #pragma unroll
  for (int nt = 0; nt < 4; ++nt)
    #pragma unroll
    for (int r = 0; r < 4; ++r) {
      int m = m0 + w * 16 + q4 + r;
      int n = n0 + nt * 16 + fm;
      x1[(size_t)m * 256 + n] = acc[nt][r] + bias[n] + resid[(size_t)m * 256 + n];
    }
}

// ---------------------------------------------------------------------------
// LN2: one wave per row of x1 [N][256] -> t2 bf16.
// ---------------------------------------------------------------------------
__global__ __launch_bounds__(256) void ln2_kernel(
    const float* __restrict__ x1, const float* __restrict__ w,
    const float* __restrict__ b, ushort* __restrict__ t2)
{
  const int tid = threadIdx.x;
  const int row = blockIdx.x * 4 + (tid >> 6);
  const int lane = tid & 63;
  floatx4 v = *(const floatx4*)(x1 + (size_t)row * 256 + lane * 4);
  float s = v[0] + v[1] + v[2] + v[3];
  float ss = v[0]*v[0] + v[1]*v[1] + v[2]*v[2] + v[3]*v[3];
  #pragma unroll
  for (int o = 32; o >= 1; o >>= 1) { s += __shfl_xor(s, o); ss += __shfl_xor(ss, o); }
  float m = s * (1.f / 256.f);
  float var = ss * (1.f / 256.f) - m * m;
  float rs = rsqrtf(var + 1e-5f);
  ushort4v o4;
  #pragma unroll
  for (int e = 0; e < 4; ++e) {
    int c = lane * 4 + e;
    o4[e] = f2bf((v[e] - m) * rs * w[c] + b[c]);
  }
  *(ushort4v*)(t2 + (size_t)row * 256 + lane * 4) = o4;
}

// ---------------------------------------------------------------------------
// fc1: [3136,256] @ [1024,256]^T + bias, gelu -> h1 bf16. grid (16,49).
// ---------------------------------------------------------------------------
__global__ __launch_bounds__(256, 2) void fc1_kernel(
    const ushort* __restrict__ A, const ushort* __restrict__ B,
    const float* __restrict__ bias, ushort* __restrict__ out)
{
  __shared__ ushort As[16384], Bs[16384];
  const int tid = threadIdx.x, lane = tid & 63, w = tid >> 6;
  const int m0 = blockIdx.y * 64, n0 = blockIdx.x * 64;
  floatx4 acc[4] = {{0.f,0.f,0.f,0.f},{0.f,0.f,0.f,0.f},
                    {0.f,0.f,0.f,0.f},{0.f,0.f,0.f,0.f}};
  stage64(A + (size_t)m0 * 256, 256, As, tid);
  stage64(B + (size_t)n0 * 256, 256, Bs, tid);
  asm volatile("s_waitcnt vmcnt(0)" ::: "memory");
  __syncthreads();
  compute64(As, Bs, w, lane, acc);
  const int fm = lane & 15, q4 = (lane >> 4) * 4;
  #pragma unroll
  for (int nt = 0; nt < 4; ++nt)
    #pragma unroll
    for (int r = 0; r < 4; ++r) {
      int m = m0 + w * 16 + q4 + r;
      int n = n0 + nt * 16 + fm;
      float v = acc[nt][r] + bias[n];
      v = 0.5f * v * (1.0f + erff(v * 0.70710678118654752f));
      out[(size_t)m * 1024 + n] = f2bf(v);
    }
}

// ---------------------------------------------------------------------------
// fc2: out[C][N] = f2w[256,1024] @ h1[3136,1024]^T + bias + x1^T. grid (49,4).
// K=1024 in 4 resident chunks.
// ---------------------------------------------------------------------------
__global__ __launch_bounds__(256, 2) void fc2_kernel(
    const ushort* __restrict__ A, const ushort* __restrict__ B,
    const float* __restrict__ bias, const float* __restrict__ x1,
    float* __restrict__ outf)
{
  __shared__ ushort As[16384], Bs[16384];
  const int tid = threadIdx.x, lane = tid & 63, w = tid >> 6;
  const int m0 = blockIdx.y * 64, n0 = blockIdx.x * 64;
  floatx4 acc[4] = {{0.f,0.f,0.f,0.f},{0.f,0.f,0.f,0.f},
                    {0.f,0.f,0.f,0.f},{0.f,0.f,0.f,0.f}};
  for (int kc = 0; kc < 4; ++kc) {
    if (kc) __syncthreads();   // all waves done reading previous chunk
    stage64(A + (size_t)m0 * 1024 + kc * 256, 1024, As, tid);
    stage64(B + (size_t)n0 * 1024 + kc * 256, 1024, Bs, tid);
    asm volatile("s_waitcnt vmcnt(0)" ::: "memory");
    __syncthreads();
    compute64(As, Bs, w, lane, acc);
  }
  const int fm = lane & 15, q4 = (lane >> 4) * 4;
  #pragma unroll
  for (int nt = 0; nt < 4; ++nt)
    #pragma unroll
    for (int r = 0; r < 4; ++r) {
      int m = m0 + w * 16 + q4 + r;       // channel
      int n = n0 + nt * 16 + fm;          // pixel
      outf[(size_t)m * 3136 + n] = acc[nt][r] + bias[m] + x1[(size_t)n * 256 + m];
    }
}

// ---------------------------------------------------------------------------
extern "C" void kernel_launch(void* const* d_in, const int* in_sizes, int n_in,
                              void* d_out, int out_size, void* d_ws, size_t ws_size,
                              hipStream_t stream) {
  const float* x     = (const float*)d_in[0];
  const float* n1w   = (const float*)d_in[1];
  const float* n1b   = (const float*)d_in[2];
  const float* qkvw  = (const float*)d_in[3];
  const float* qkvb  = (const float*)d_in[4];
  const float* projw = (const float*)d_in[5];
  const float* projb = (const float*)d_in[6];
  const float* n2w   = (const float*)d_in[7];
  const float* n2b   = (const float*)d_in[8];
  const float* f1w   = (const float*)d_in[9];
  const float* f1b   = (const float*)d_in[10];
  const float* f2w   = (const float*)d_in[11];
  const float* f2b   = (const float*)d_in[12];

  char* ws = (char*)d_ws;
  ushort* wcat = (ushort*)(ws + 0);            // 786432 bf16
  float*  xT   = (float*)(ws + 1572864);       // 802816 f32 (xT, then x1 in-place)
  ushort* t    = (ushort*)(ws + 4784128);      // 802816 bf16 (t1, then t2)
  ushort* qh   = (ushort*)(ws + 6389760);      // qkv [3136][768], then h1 [3136][1024]
  ushort* attnO= (ushort*)(ws + 12812288);     // 802816 bf16

  const ushort* qw_bf = wcat;
  const ushort* pw_bf = wcat + 196608;
  const ushort* f1_bf = wcat + 262144;
  const ushort* f2_bf = wcat + 524288;
  float* outf = (float*)d_out;

  hipLaunchKernelGGL(prep_kernel, dim3(3268), dim3(256), 0, stream,
                     x, n1w, n1b, qkvw, projw, f1w, f2w, xT, t, wcat);
  hipLaunchKernelGGL(qkv_kernel, dim3(12, 49), dim3(256), 0, stream,
                     t, qw_bf, qkvb, qh);
  hipLaunchKernelGGL(attn_kernel, dim3(3136), dim3(256), 0, stream, qh, attnO);
  hipLaunchKernelGGL(proj_kernel, dim3(4, 49), dim3(256), 0, stream,
                     attnO, pw_bf, projb, xT, xT);
  hipLaunchKernelGGL(ln2_kernel, dim3(784), dim3(256), 0, stream,
                     xT, n2w, n2b, t);
  hipLaunchKernelGGL(fc1_kernel, dim3(16, 49), dim3(256), 0, stream,
                     t, f1_bf, f1b, qh);
  hipLaunchKernelGGL(fc2_kernel, dim3(49, 4), dim3(256), 0, stream,
                     f2_bf, qh, f2b, xT, outf);
}

// Round 5
// 147.049 us; speedup vs baseline: 3.8607x; 1.0488x over previous
//
#include <hip/hip_runtime.h>
#include <math.h>

// ---------------------------------------------------------------------------
// LocalTransformerBlock2d: B=1, C=256, H=W=56 (N=3136), 8 heads x d=32,
// 7x7 local window. fp32 in/out; bf16 MFMA GEMMs.
// 6 stream-ordered kernels:
//   prep(cvt+LN1T) -> qkv -> attn(halo-LDS) -> proj(+resid) ->
//   fc1(+LN2 fused, +gelu) -> fc2(+resid, transposed out)
// Overhead model (R2 evidence): ~89us fixed harness overhead + ~3.5us/node;
// device kernels sum ~40us. attn was the largest kernel (DS/VMEM-pipe bound);
// this round vectorizes it 8ch/lane from an LDS halo.
// ---------------------------------------------------------------------------

typedef unsigned int uint;
typedef unsigned short ushort;
typedef unsigned long long u64;
typedef __attribute__((ext_vector_type(8))) short short8;   // 8 bf16
typedef __attribute__((ext_vector_type(4))) float floatx4;  // MFMA acc
typedef __attribute__((ext_vector_type(4))) unsigned short ushort4v;

#define AS1(p) (const __attribute__((address_space(1))) void*)(p)
#define AS3(p) (__attribute__((address_space(3))) void*)(p)

__device__ __forceinline__ float bf2f(ushort u) {
  union { uint i; float f; } v; v.i = ((uint)u) << 16; return v.f;
}
__device__ __forceinline__ ushort f2bf(float f) {
  union { float f; uint i; } v; v.f = f;
  uint u = v.i;
  return (ushort)((u + 0x7fffu + ((u >> 16) & 1u)) >> 16);
}

// Stage a 64-row x 256-col bf16 panel into LDS with XOR swizzle.
// LDS slot (row, cb) holds global col-block (cb ^ (row&7)).
__device__ __forceinline__ void stage64(const ushort* src, int kstride,
                                        ushort* dstBase, int tid) {
  const int srow = tid >> 5;                 // 0..7
  const int scb  = (tid & 31) ^ srow;        // permuted 16B block
  const ushort* g = src + (size_t)srow * kstride + scb * 8;
  ushort* d = dstBase + tid * 8;             // wave-uniform base + lane*16B
  #pragma unroll
  for (int r = 0; r < 8; ++r) {
    __builtin_amdgcn_global_load_lds(AS1(g), AS3(d), 16, 0, 0);
    g += 8 * kstride;
    d += 2048;
  }
}

// 8 k-iters over resident K=256 panels; 4 n-subtiles per wave.
__device__ __forceinline__ void compute64(const ushort* As, const ushort* Bs,
                                          int w, int lane, floatx4 acc[4]) {
  const int fm = lane & 15;
  const int q  = lane >> 4;
  const int swz = fm & 7;
  const int arow = (w * 16 + fm) * 256;
  #pragma unroll
  for (int kt = 0; kt < 8; ++kt) {
    const int blk = ((kt * 4 + q) ^ swz) * 8;
    short8 af = *(const short8*)&As[arow + blk];
    #pragma unroll
    for (int nt = 0; nt < 4; ++nt) {
      short8 bfr = *(const short8*)&Bs[(nt * 16 + fm) * 256 + blk];
      acc[nt] = __builtin_amdgcn_mfma_f32_16x16x32_bf16(af, bfr, acc[nt], 0, 0, 0);
    }
  }
}

// ---------------------------------------------------------------------------
// prep: blocks 0..195 LN1+transpose (16 px each); blocks 196+ weight cvt.
// ---------------------------------------------------------------------------
__global__ __launch_bounds__(256) void prep_kernel(
    const float* __restrict__ x, const float* __restrict__ n1w,
    const float* __restrict__ n1b,
    const float* __restrict__ qkvw, const float* __restrict__ projw,
    const float* __restrict__ f1w, const float* __restrict__ f2w,
    float* __restrict__ xT, ushort* __restrict__ t1, ushort* __restrict__ wcat)
{
  const int tid = threadIdx.x;
  const int bid = blockIdx.x;
  if (bid >= 196) {
    int idx = (bid - 196) * 256 + tid;
    float v;
    if (idx < 196608)       v = qkvw[idx];
    else if (idx < 262144)  v = projw[idx - 196608];
    else if (idx < 524288)  v = f1w[idx - 262144];
    else                    v = f2w[idx - 524288];
    wcat[idx] = f2bf(v);
    return;
  }
  __shared__ float tile[256 * 17];
  __shared__ float red[2][16][16];
  __shared__ float mu[16], rsv[16];
  const int n0 = bid * 16;
  const int px = tid & 15, grp = tid >> 4;
  #pragma unroll 4
  for (int it = 0; it < 16; ++it) {
    int c = it * 16 + grp;
    tile[c * 17 + px] = x[(size_t)c * 3136 + n0 + px];
  }
  __syncthreads();
  float s = 0.f, ss = 0.f;
  #pragma unroll
  for (int i = 0; i < 16; ++i) {
    float v = tile[(grp * 16 + i) * 17 + px];
    s += v; ss += v * v;
  }
  red[0][px][grp] = s; red[1][px][grp] = ss;
  __syncthreads();
  if (tid < 16) {
    float s2 = 0.f, ss2 = 0.f;
    #pragma unroll
    for (int g = 0; g < 16; ++g) { s2 += red[0][tid][g]; ss2 += red[1][tid][g]; }
    float m = s2 * (1.f / 256.f);
    float var = ss2 * (1.f / 256.f) - m * m;
    mu[tid] = m;
    rsv[tid] = rsqrtf(var + 1e-5f);
  }
  __syncthreads();
  const float wc = n1w[tid], bc = n1b[tid];
  #pragma unroll 4
  for (int p = 0; p < 16; ++p) {
    float v = tile[tid * 17 + p];
    xT[(size_t)(n0 + p) * 256 + tid] = v;
    t1[(size_t)(n0 + p) * 256 + tid] = f2bf((v - mu[p]) * rsv[p] * wc + bc);
  }
}

// ---------------------------------------------------------------------------
// qkv: [3136,256] @ [768,256]^T + bias (q scaled). grid (12,49).
// ---------------------------------------------------------------------------
__global__ __launch_bounds__(256, 2) void qkv_kernel(
    const ushort* __restrict__ A, const ushort* __restrict__ B,
    const float* __restrict__ bias, ushort* __restrict__ out)
{
  __shared__ ushort As[16384], Bs[16384];
  const int tid = threadIdx.x, lane = tid & 63, w = tid >> 6;
  const int m0 = blockIdx.y * 64, n0 = blockIdx.x * 64;
  floatx4 acc[4] = {{0.f,0.f,0.f,0.f},{0.f,0.f,0.f,0.f},
                    {0.f,0.f,0.f,0.f},{0.f,0.f,0.f,0.f}};
  stage64(A + (size_t)m0 * 256, 256, As, tid);
  stage64(B + (size_t)n0 * 256, 256, Bs, tid);
  asm volatile("s_waitcnt vmcnt(0)" ::: "memory");
  __syncthreads();
  compute64(As, Bs, w, lane, acc);
  const int fm = lane & 15, q4 = (lane >> 4) * 4;
  #pragma unroll
  for (int nt = 0; nt < 4; ++nt)
    #pragma unroll
    for (int r = 0; r < 4; ++r) {
      int m = m0 + w * 16 + q4 + r;
      int n = n0 + nt * 16 + fm;
      float v = acc[nt][r] + bias[n];
      if (n < 256) v *= 0.17677669529663687f;   // 1/sqrt(32) on q
      out[(size_t)m * 768 + n] = f2bf(v);
    }
}

// ---------------------------------------------------------------------------
// attn: 4x4 query tile per block (grid 196 = 14x14), 256 threads.
// K/V halo (10x10 px) staged in LDS once. Scores: wave = 4 queries,
// lane = (head, slot-group of 8). PV: 8 channels/lane via b128 V reads.
// LDS: Kh 100x260 (pad to temper bank aliasing) + Vh 100x256 + pr[16][8][64].
// ---------------------------------------------------------------------------
__global__ __launch_bounds__(256, 1) void attn_kernel(
    const ushort* __restrict__ qkv, ushort* __restrict__ out)
{
  __shared__ ushort Kh[100 * 260];
  __shared__ ushort Vh[100 * 256];
  __shared__ float pr[16 * 8 * 64];
  const int tid = threadIdx.x;
  const int i0 = (blockIdx.x / 14) * 4, j0 = (blockIdx.x % 14) * 4;

  // ---- halo load (zero-fill out-of-image rows) ----
  for (int s = tid; s < 3200; s += 256) {
    int p = s >> 5, ck = s & 31;
    int ii = i0 - 3 + p / 10, jj = j0 - 3 + p % 10;
    if (ii >= 0 && ii < 56 && jj >= 0 && jj < 56) {
      const ushort* kr = qkv + (size_t)(ii * 56 + jj) * 768 + 256 + ck * 8;
      short8 kv = *(const short8*)kr;           // 16B aligned
      u64 lo = ((const u64*)&kv)[0], hi = ((const u64*)&kv)[1];
      *(u64*)&Kh[p * 260 + ck * 8] = lo;        // 8B-aligned (stride 520B)
      *(u64*)&Kh[p * 260 + ck * 8 + 4] = hi;
      *(short8*)&Vh[p * 256 + ck * 8] = *(const short8*)(kr + 256);
    } else {
      *(u64*)&Kh[p * 260 + ck * 8] = 0ull;
      *(u64*)&Kh[p * 260 + ck * 8 + 4] = 0ull;
      short8 z = {0, 0, 0, 0, 0, 0, 0, 0};
      *(short8*)&Vh[p * 256 + ck * 8] = z;
    }
  }
  __syncthreads();

  // ---- scores + softmax: wave wv owns queries 4wv..4wv+3 ----
  const int wv = tid >> 6, lane = tid & 63;
  const int h = lane >> 3, mg = lane & 7;      // head, slot-group
  for (int qq = 0; qq < 4; ++qq) {
    const int p = wv * 4 + qq;
    const int qi = p >> 2, qj = p & 3;
    const int iq = i0 + qi, jq = j0 + qj;
    const ushort* qp = qkv + (size_t)(iq * 56 + jq) * 768 + h * 32;
    float qf[32];
    #pragma unroll
    for (int u = 0; u < 4; ++u) {
      short8 qv = *(const short8*)(qp + u * 8);
      #pragma unroll
      for (int e = 0; e < 8; ++e) qf[u * 8 + e] = bf2f((ushort)qv[e]);
    }
    float sv[7];
    float mx = -1e30f;
    #pragma unroll
    for (int k = 0; k < 7; ++k) {
      int m = mg + 8 * k;
      float s = -1e30f;
      if (m < 49) {
        int mi = m / 7, mj = m % 7;
        int ii = iq + mi - 3, jj = jq + mj - 3;
        if (ii >= 0 && ii < 56 && jj >= 0 && jj < 56) {
          int hrow = (qi + mi) * 10 + (qj + mj);
          const u64* k8 = (const u64*)&Kh[hrow * 260 + h * 32];
          float a = 0.f;
          #pragma unroll
          for (int u = 0; u < 8; ++u) {
            u64 kv = k8[u];
            #pragma unroll
            for (int e = 0; e < 4; ++e)
              a += qf[u * 4 + e] * bf2f((ushort)(kv >> (16 * e)));
          }
          s = a;
        }
      }
      sv[k] = s;
      mx = fmaxf(mx, s);
    }
    mx = fmaxf(mx, __shfl_xor(mx, 1));
    mx = fmaxf(mx, __shfl_xor(mx, 2));
    mx = fmaxf(mx, __shfl_xor(mx, 4));
    float sm = 0.f;
    #pragma unroll
    for (int k = 0; k < 7; ++k) { sv[k] = __expf(sv[k] - mx); sm += sv[k]; }
    sm += __shfl_xor(sm, 1);
    sm += __shfl_xor(sm, 2);
    sm += __shfl_xor(sm, 4);
    float inv = 1.f / sm;
    #pragma unroll
    for (int k = 0; k < 7; ++k) {
      int m = mg + 8 * k;                      // <= 55 < 64
      pr[(p * 8 + h) * 64 + m] = sv[k] * inv;  // invalid slots are exact 0
    }
  }
  __syncthreads();

  // ---- PV: thread = (qsel, 8-channel group); 2 passes cover 16 queries ----
  const int qsel = tid >> 5, cg = tid & 31, hh = cg >> 2;
  #pragma unroll
  for (int pass = 0; pass < 2; ++pass) {
    const int p = pass * 8 + qsel;
    const int qi = p >> 2, qj = p & 3;
    float acc8[8] = {0, 0, 0, 0, 0, 0, 0, 0};
    #pragma unroll
    for (int mi = 0; mi < 7; ++mi)
      #pragma unroll
      for (int mj = 0; mj < 7; ++mj) {
        int m = mi * 7 + mj;
        int hrow = (qi + mi) * 10 + (qj + mj);
        float pm = pr[(p * 8 + hh) * 64 + m];  // 0 for out-of-image
        short8 v8 = *(const short8*)&Vh[hrow * 256 + cg * 8];
        #pragma unroll
        for (int e = 0; e < 8; ++e)
          acc8[e] += pm * bf2f((ushort)v8[e]);
      }
    const int n = (i0 + qi) * 56 + (j0 + qj);
    short8 o;
    #pragma unroll
    for (int e = 0; e < 8; ++e) o[e] = (short)f2bf(acc8[e]);
    *(short8*)&out[(size_t)n * 256 + cg * 8] = o;
  }
}

// ---------------------------------------------------------------------------
// proj: [3136,256] @ [256,256]^T + bias + resid -> x1 fp32. grid (4,49).
// ---------------------------------------------------------------------------
__global__ __launch_bounds__(256, 2) void proj_kernel(
    const ushort* __restrict__ A, const ushort* __restrict__ B,
    const float* __restrict__ bias, const float* __restrict__ resid,
    float* __restrict__ x1)
{
  __shared__ ushort As[16384], Bs[16384];
  const int tid = threadIdx.x, lane = tid & 63, w = tid >> 6;
  const int m0 = blockIdx.y * 64, n0 = blockIdx.x * 64;
  floatx4 acc[4] = {{0.f,0.f,0.f,0.f},{0.f,0.f,0.f,0.f},
                    {0.f,0.f,0.f,0.f},{0.f,0.f,0.f,0.f}};
  stage64(A + (size_t)m0 * 256, 256, As, tid);
  stage64(B + (size_t)n0 * 256, 256, Bs, tid);
  asm volatile("s_waitcnt vmcnt(0)" ::: "memory");
  __syncthreads();
  compute64(As, Bs, w, lane, acc);
  const int fm = lane & 15, q4 = (lane >> 4) * 4;
  #pragma unroll
  for (int nt = 0; nt < 4; ++nt)
    #pragma unroll
    for (int r = 0; r < 4; ++r) {
      int m = m0 + w * 16 + q4 + r;
      int n = n0 + nt * 16 + fm;
      x1[(size_t)m * 256 + n] = acc[nt][r] + bias[n] + resid[(size_t)m * 256 + n];
    }
}

// ---------------------------------------------------------------------------
// fc1 (+LN2 fused): A = LN2(x1[m0:m0+64][0:256]) normalized in-block,
// D = A @ f1w[1024,256]^T + bias, gelu -> h1 bf16. grid (16,49).
// ---------------------------------------------------------------------------
__global__ __launch_bounds__(256, 2) void fc1_kernel(
    const float* __restrict__ x1, const ushort* __restrict__ B,
    const float* __restrict__ n2w, const float* __restrict__ n2b,
    const float* __restrict__ bias, ushort* __restrict__ out)
{
  __shared__ ushort As[16384], Bs[16384];
  __shared__ float stats[128];               // 64 rows x {mu, rs}
  const int tid = threadIdx.x, lane = tid & 63, w = tid >> 6;
  const int m0 = blockIdx.y * 64, n0 = blockIdx.x * 64;

  stage64(B + (size_t)n0 * 256, 256, Bs, tid);   // B DMA in flight during LN

  // row stats: 4 threads per row
  {
    const int r = tid >> 2, seg = tid & 3;
    const float* src = x1 + (size_t)(m0 + r) * 256 + seg * 64;
    float s = 0.f, ss = 0.f;
    #pragma unroll
    for (int i = 0; i < 16; ++i) {
      floatx4 v = *(const floatx4*)(src + i * 4);
      s += v[0] + v[1] + v[2] + v[3];
      ss += v[0]*v[0] + v[1]*v[1] + v[2]*v[2] + v[3]*v[3];
    }
    s += __shfl_xor(s, 1); ss += __shfl_xor(ss, 1);
    s += __shfl_xor(s, 2); ss += __shfl_xor(ss, 2);
    if (seg == 0) {
      float mu = s * (1.f / 256.f);
      float var = ss * (1.f / 256.f) - mu * mu;
      stats[r * 2] = mu;
      stats[r * 2 + 1] = rsqrtf(var + 1e-5f);
    }
  }
  __syncthreads();
  // normalize into swizzled As: 8 slots (16B) per thread
  #pragma unroll
  for (int k = 0; k < 8; ++k) {
    int s = tid + k * 256;
    int row = s >> 5, cb = s & 31;
    int gb = cb ^ (row & 7);
    float mu = stats[row * 2], rs = stats[row * 2 + 1];
    const float* src = x1 + (size_t)(m0 + row) * 256 + gb * 8;
    floatx4 a = *(const floatx4*)(src);
    floatx4 b2 = *(const floatx4*)(src + 4);
    floatx4 w1 = *(const floatx4*)(n2w + gb * 8);
    floatx4 w2 = *(const floatx4*)(n2w + gb * 8 + 4);
    floatx4 b1v = *(const floatx4*)(n2b + gb * 8);
    floatx4 b2v = *(const floatx4*)(n2b + gb * 8 + 4);
    short8 o;
    #pragma unroll
    for (int e = 0; e < 4; ++e) {
      o[e]     = (short)f2bf((a[e]  - mu) * rs * w1[e] + b1v[e]);
      o[e + 4] = (short)f2bf((b2[e] - mu) * rs * w2[e] + b2v[e]);
    }
    *(short8*)&As[row * 256 + cb * 8] = o;
  }
  asm volatile("s_waitcnt vmcnt(0)" ::: "memory");
  __syncthreads();

  floatx4 acc[4] = {{0.f,0.f,0.f,0.f},{0.f,0.f,0.f,0.f},
                    {0.f,0.f,0.f,0.f},{0.f,0.f,0.f,0.f}};
  compute64(As, Bs, w, lane, acc);
  const int fm = lane & 15, q4 = (lane >> 4) * 4;
  #pragma unroll
  for (int nt = 0; nt < 4; ++nt)
    #pragma unroll
    for (int r = 0; r < 4; ++r) {
      int m = m0 + w * 16 + q4 + r;
      int n = n0 + nt * 16 + fm;
      float v = acc[nt][r] + bias[n];
      v = 0.5f * v * (1.0f + erff(v * 0.70710678118654752f));
      out[(size_t)m * 1024 + n] = f2bf(v);
    }
}

// ---------------------------------------------------------------------------
// fc2: out[C][N] = f2w[256,1024] @ h1[3136,1024]^T + bias + x1^T. grid (49,4).
// ---------------------------------------------------------------------------
__global__ __launch_bounds__(256, 2) void fc2_kernel(
    const ushort* __restrict__ A, const ushort* __restrict__ B,
    const float* __restrict__ bias, const float* __restrict__ x1,
    float* __restrict__ outf)
{
  __shared__ ushort As[16384], Bs[16384];
  const int tid = threadIdx.x, lane = tid & 63, w = tid >> 6;
  const int m0 = blockIdx.y * 64, n0 = blockIdx.x * 64;
  floatx4 acc[4] = {{0.f,0.f,0.f,0.f},{0.f,0.f,0.f,0.f},
                    {0.f,0.f,0.f,0.f},{0.f,0.f,0.f,0.f}};
  for (int kc = 0; kc < 4; ++kc) {
    if (kc) __syncthreads();
    stage64(A + (size_t)m0 * 1024 + kc * 256, 1024, As, tid);
    stage64(B + (size_t)n0 * 1024 + kc * 256, 1024, Bs, tid);
    asm volatile("s_waitcnt vmcnt(0)" ::: "memory");
    __syncthreads();
    compute64(As, Bs, w, lane, acc);
  }
  const int fm = lane & 15, q4 = (lane >> 4) * 4;
  #pragma unroll
  for (int nt = 0; nt < 4; ++nt)
    #pragma unroll
    for (int r = 0; r < 4; ++r) {
      int m = m0 + w * 16 + q4 + r;       // channel
      int n = n0 + nt * 16 + fm;          // pixel
      outf[(size_t)m * 3136 + n] = acc[nt][r] + bias[m] + x1[(size_t)n * 256 + m];
    }
}

// ---------------------------------------------------------------------------
extern "C" void kernel_launch(void* const* d_in, const int* in_sizes, int n_in,
                              void* d_out, int out_size, void* d_ws, size_t ws_size,
                              hipStream_t stream) {
  const float* x     = (const float*)d_in[0];
  const float* n1w   = (const float*)d_in[1];
  const float* n1b   = (const float*)d_in[2];
  const float* qkvw  = (const float*)d_in[3];
  const float* qkvb  = (const float*)d_in[4];
  const float* projw = (const float*)d_in[5];
  const float* projb = (const float*)d_in[6];
  const float* n2w   = (const float*)d_in[7];
  const float* n2b   = (const float*)d_in[8];
  const float* f1w   = (const float*)d_in[9];
  const float* f1b   = (const float*)d_in[10];
  const float* f2w   = (const float*)d_in[11];
  const float* f2b   = (const float*)d_in[12];

  char* ws = (char*)d_ws;
  ushort* wcat = (ushort*)(ws + 0);            // 786432 bf16
  float*  xT   = (float*)(ws + 1572864);       // 802816 f32 (xT, then x1 in-place)
  ushort* t    = (ushort*)(ws + 4784128);      // 802816 bf16 (t1)
  ushort* qh   = (ushort*)(ws + 6389760);      // qkv [3136][768], then h1 [3136][1024]
  ushort* attnO= (ushort*)(ws + 12812288);     // 802816 bf16

  const ushort* qw_bf = wcat;
  const ushort* pw_bf = wcat + 196608;
  const ushort* f1_bf = wcat + 262144;
  const ushort* f2_bf = wcat + 524288;
  float* outf = (float*)d_out;

  hipLaunchKernelGGL(prep_kernel, dim3(3268), dim3(256), 0, stream,
                     x, n1w, n1b, qkvw, projw, f1w, f2w, xT, t, wcat);
  hipLaunchKernelGGL(qkv_kernel, dim3(12, 49), dim3(256), 0, stream,
                     t, qw_bf, qkvb, qh);
  hipLaunchKernelGGL(attn_kernel, dim3(196), dim3(256), 0, stream, qh, attnO);
  hipLaunchKernelGGL(proj_kernel, dim3(4, 49), dim3(256), 0, stream,
                     attnO, pw_bf, projb, xT, xT);
  hipLaunchKernelGGL(fc1_kernel, dim3(16, 49), dim3(256), 0, stream,
                     xT, f1_bf, n2w, n2b, f1b, qh);
  hipLaunchKernelGGL(fc2_kernel, dim3(49, 4), dim3(256), 0, stream,
                     f2_bf, qh, f2b, xT, outf);
}